// Round 1
// 163.806 us; speedup vs baseline: 1.0547x; 1.0547x over previous
//
#include <hip/hip_runtime.h>
#include <math.h>

// ---------------------------------------------------------------------------
// QConv2dMedium: quantum conv = per-pixel 16-ch map
//   out[k] = clip(8 * |U[k,0:9] . p|^2 / max(||p||,1e-12)^2, 0, 1)
// U = (CNOT perms L1)(Layer1)(CNOT perms L0)(Layer0), 16x16 complex.
//
// R1: qconv was LDS-instruction-throughput bound (288 broadcast ds_read_b32
// of U per pixel ~= 89 us/CU budget). Now: 4 pixels/thread (one row, 4 cols,
// float4 stores) + U packed interleaved (re,im) so each k row is read with
// 4x ds_read_b128 + 1x ds_read_b64, amortized over 4 pixels.
// ---------------------------------------------------------------------------

#define WIRES 4
#define DIM 16

// Rot(phi, theta, omega) entry [rb][cb] of wire i's 2x2, as complex (er, ei)
__device__ inline void rot_entry(float phi, float th, float om, int rb, int cb,
                                 float& er, float& ei) {
    float a = 0.5f * (phi + om);
    float b = 0.5f * (phi - om);
    float cc = cosf(0.5f * th), ss = sinf(0.5f * th);
    if (rb == 0 && cb == 0) { er = cc * cosf(a); ei = -cc * sinf(a); }
    else if (rb == 0 && cb == 1) { er = -ss * cosf(b); ei = -ss * sinf(b); }
    else if (rb == 1 && cb == 0) { er = ss * cosf(b); ei = -ss * sinf(b); }
    else { er = cc * cosf(a); ei = cc * sinf(a); }
}

// layer element L[r][c] = prod_i R_i[bit_i(r)][bit_i(c)], bit_i = bit (3-i)
__device__ inline void layer_elem(const float* __restrict__ w, int l, int r,
                                  int c, float& pr, float& pi) {
    pr = 1.f; pi = 0.f;
    #pragma unroll
    for (int i = 0; i < WIRES; ++i) {
        const float* wi = w + (l * WIRES + i) * 3;
        float er, ei;
        int rb = (r >> (3 - i)) & 1, cb = (c >> (3 - i)) & 1;
        rot_entry(wi[0], wi[1], wi[2], rb, cb, er, ei);
        float nr = pr * er - pi * ei;
        float ni = pr * ei + pi * er;
        pr = nr; pi = ni;
    }
}

// source row after applying the layer-l CNOT chain (dest row r reads src row)
__device__ inline int cnot_src(int r, int range) {
    int src = r;
    // U_final[j] = U[p0(p1(p2(p3(j))))] -> apply p3 first
    #pragma unroll
    for (int i = WIRES - 1; i >= 0; --i) {
        int control = i, target = (i + range) & 3;
        int cbit = 1 << (3 - control), tbit = 1 << (3 - target);
        if (src & cbit) src ^= tbit;
    }
    return src;
}

__global__ __launch_bounds__(256) void build_unitary(
        const float* __restrict__ w, float* __restrict__ uout) {
    __shared__ float Lr[DIM][DIM], Li[DIM][DIM];
    __shared__ float Ur[DIM][DIM], Ui[DIM][DIM];
    __shared__ float Tr[DIM][DIM], Ti[DIM][DIM];
    int t = threadIdx.x;
    int r = t >> 4, c = t & 15;

    // ---- layer 0 (U starts as identity, so U = L0) ----
    float lr, li;
    layer_elem(w, 0, r, c, lr, li);
    Lr[r][c] = lr; Li[r][c] = li;
    __syncthreads();
    // CNOT perms, range = 0 % 3 + 1 = 1
    int s0 = cnot_src(r, 1);
    Ur[r][c] = Lr[s0][c]; Ui[r][c] = Li[s0][c];
    __syncthreads();

    // ---- layer 1: T = L1 @ U ----
    layer_elem(w, 1, r, c, lr, li);
    Lr[r][c] = lr; Li[r][c] = li;
    __syncthreads();
    float ar = 0.f, ai = 0.f;
    #pragma unroll
    for (int m = 0; m < DIM; ++m) {
        float xr = Lr[r][m], xi = Li[r][m];
        float yr = Ur[m][c], yi = Ui[m][c];
        ar += xr * yr - xi * yi;
        ai += xr * yi + xi * yr;
    }
    Tr[r][c] = ar; Ti[r][c] = ai;
    __syncthreads();
    // CNOT perms, range = 1 % 3 + 1 = 2
    // Pack only what qconv needs: rows k=0..15, cols m=0..8, interleaved
    // (re,im), row stride 20 floats (80 B -> 16 B aligned per row).
    int s1 = cnot_src(r, 2);
    if (c < 9) {
        uout[r * 20 + 2 * c]     = Tr[s1][c];
        uout[r * 20 + 2 * c + 1] = Ti[s1][c];
    }
}

#define H 256
#define W 256
#define NB 32
#define OUTC 16
#define RPB 4   // output rows per block; thread t: row t>>6, cols 4*(t&63)..+3

__global__ __launch_bounds__(256) void qconv_kernel(
        const float* __restrict__ x, const float* __restrict__ u,
        float* __restrict__ out) {
    __shared__ float sU[OUTC][20];          // interleaved re,im; 18 used/row
    __shared__ float rows[RPB + 2][W + 8];  // rows[wr][j+1] = x[i0-1+wr][j]

    int t = threadIdx.x;
    int blk = blockIdx.x;            // 0 .. NB*H/RPB - 1
    int b = blk >> 6;                // 64 row-groups per image
    int i0 = (blk & 63) << 2;

    // ---- stage U (320 floats) ----
    {
        float* sUf = &sU[0][0];
        sUf[t & 255] = u[t & 255];   // t<256 always
        if (t < 64) sUf[t + 256] = u[t + 256];
    }

    // ---- stage 6 input rows (with 0.01 halo) ----
    const float* xb = x + (size_t)b * (H * W);
    #pragma unroll
    for (int wr = 0; wr < RPB + 2; ++wr) {
        int row = i0 + wr - 1;
        bool rok = (unsigned)row < (unsigned)H;
        for (int cpos = t; cpos < W + 2; cpos += 256) {
            int j = cpos - 1;
            float v = 0.01f;
            if (rok && (unsigned)j < (unsigned)W) v = xb[row * W + j];
            rows[wr][cpos] = v;
        }
    }
    __syncthreads();

    int rl = t >> 6;                 // local output row 0..3
    int c  = (t & 63) << 2;          // column base 0..252 (16B-aligned)
    int i  = i0 + rl;

    // ---- sliding window: 3 input rows x 6 cols (cols c-1 .. c+4 of x) ----
    float win[3][6];
    #pragma unroll
    for (int di = 0; di < 3; ++di) {
        float4 a = *(const float4*)&rows[rl + di][c];       // u=0..3
        float4 bq = *(const float4*)&rows[rl + di][c + 4];  // u=4..7 (6,7 unused)
        win[di][0] = a.x;  win[di][1] = a.y;  win[di][2] = a.z;
        win[di][3] = a.w;  win[di][4] = bq.x; win[di][5] = bq.y;
    }

    // ---- per-pixel norm factor ----
    float fac[4];
    #pragma unroll
    for (int px = 0; px < 4; ++px) {
        float n2 = 0.f;
        #pragma unroll
        for (int di = 0; di < 3; ++di)
            #pragma unroll
            for (int dj = 0; dj < 3; ++dj) {
                float pv = win[di][px + dj];
                n2 = fmaf(pv, pv, n2);
            }
        // (DIM*0.5)/max(||p||,1e-12)^2 ; max(n,e)^2 == max(n^2,e^2) for n>=0
        fac[px] = 8.0f / fmaxf(n2, 1e-24f);
    }

    // ---- 16 channels, 4 pixels each; float4 coalesced stores ----
    float* ob = out + (size_t)b * OUTC * (H * W) + (size_t)i * W + c;
    #pragma unroll
    for (int k = 0; k < OUTC; ++k) {
        float4 q0 = *(const float4*)&sU[k][0];    // m0,m1 (re,im)
        float4 q1 = *(const float4*)&sU[k][4];    // m2,m3
        float4 q2 = *(const float4*)&sU[k][8];    // m4,m5
        float4 q3 = *(const float4*)&sU[k][12];   // m6,m7
        float2 q4 = *(const float2*)&sU[k][16];   // m8
        float4 res;
        #pragma unroll
        for (int px = 0; px < 4; ++px) {
            float sr, si;
            sr = q0.x * win[0][px];                                 // m0
            si = q0.y * win[0][px];
            sr = fmaf(q0.z, win[0][px + 1], sr);                    // m1
            si = fmaf(q0.w, win[0][px + 1], si);
            sr = fmaf(q1.x, win[0][px + 2], sr);                    // m2
            si = fmaf(q1.y, win[0][px + 2], si);
            sr = fmaf(q1.z, win[1][px], sr);                        // m3
            si = fmaf(q1.w, win[1][px], si);
            sr = fmaf(q2.x, win[1][px + 1], sr);                    // m4
            si = fmaf(q2.y, win[1][px + 1], si);
            sr = fmaf(q2.z, win[1][px + 2], sr);                    // m5
            si = fmaf(q2.w, win[1][px + 2], si);
            sr = fmaf(q3.x, win[2][px], sr);                        // m6
            si = fmaf(q3.y, win[2][px], si);
            sr = fmaf(q3.z, win[2][px + 1], sr);                    // m7
            si = fmaf(q3.w, win[2][px + 1], si);
            sr = fmaf(q4.x, win[2][px + 2], sr);                    // m8
            si = fmaf(q4.y, win[2][px + 2], si);
            float v = fac[px] * fmaf(sr, sr, si * si);
            ((float*)&res)[px] = fminf(v, 1.0f);
        }
        *(float4*)&ob[(size_t)k * (H * W)] = res;
    }
}

extern "C" void kernel_launch(void* const* d_in, const int* in_sizes, int n_in,
                              void* d_out, int out_size, void* d_ws, size_t ws_size,
                              hipStream_t stream) {
    const float* x = (const float*)d_in[0];        // (32,1,256,256) fp32
    const float* w = (const float*)d_in[1];        // (2,4,3) fp32
    float* out = (float*)d_out;                    // (32,16,256,256) fp32
    float* uws = (float*)d_ws;                     // 320 floats packed (re,im)

    build_unitary<<<1, 256, 0, stream>>>(w, uws);
    qconv_kernel<<<NB * H / RPB, 256, 0, stream>>>(x, uws, out);
}